// Round 5
// baseline (1204.950 us; speedup 1.0000x reference)
//
#include <hip/hip_runtime.h>
#include <cstdint>
#include <cstddef>

#define N_INS    16384
#define INS_DIM  2048
#define N_CLS    81
#define BANK     10
#define CMAX     288    // max instances/class (mean 202, sd 14; fixed seed max ~252)
#define EXT      304    // extended Gram dim/stride: 10 + CMAX + pad
#define GR_TILES 9      // 128x64 tiles covering upper triangle of EXT x EXT
#define N_CLSBLK (N_INS / 64)          // 256 classify blocks, FIRST in grid
#define GRID_ALL (N_CLSBLK + N_CLS * GR_TILES)

// ---------------------------------------------------------------------------
// Kernel 1: fused prep (mean + ||mean||^2) and per-class ordered list build
// ---------------------------------------------------------------------------
__global__ __launch_bounds__(256)
void prep_list_kernel(const float* __restrict__ memory,
                      const int*   __restrict__ labels,
                      float* __restrict__ mean_out,   // [81][2048]
                      float* __restrict__ base_out,   // [81]
                      int* __restrict__ g_list,       // [81][CMAX]
                      int* __restrict__ g_cnt)        // [81]
{
    __shared__ double sred[4];
    __shared__ int s_wcnt[4];
    __shared__ int s_cnt;
    const int t = threadIdx.x;
    const int w = t >> 6, lane = t & 63;

    if (blockIdx.x < N_CLS) {
        const int c = blockIdx.x;
        double nrm = 0.0;
        #pragma unroll
        for (int rep = 0; rep < 2; ++rep) {
            const int d4 = (t + rep * 256) * 4;
            float sx = 0.f, sy = 0.f, sz = 0.f, sw = 0.f;
            #pragma unroll
            for (int b = 0; b < BANK; ++b) {
                const float4 v = *(const float4*)(memory + ((size_t)(c * BANK + b)) * INS_DIM + d4);
                sx += v.x; sy += v.y; sz += v.z; sw += v.w;
            }
            sx /= 10.0f; sy /= 10.0f; sz /= 10.0f; sw /= 10.0f;
            *(float4*)(mean_out + (size_t)c * INS_DIM + d4) = make_float4(sx, sy, sz, sw);
            nrm += (double)sx * sx + (double)sy * sy + (double)sz * sz + (double)sw * sw;
        }
        #pragma unroll
        for (int off = 32; off >= 1; off >>= 1) nrm += __shfl_xor(nrm, off, 64);
        if (lane == 0) sred[w] = nrm;
        __syncthreads();
        if (t == 0) base_out[c] = (float)(sred[0] + sred[1] + sred[2] + sred[3]);
    } else {
        const int c = blockIdx.x - N_CLS;
        if (t == 0) s_cnt = 0;
        __syncthreads();
        for (int base = 0; base < N_INS; base += 256) {
            const int idx = base + t;
            const bool match = (labels[idx] == c);
            const unsigned long long mb = __ballot(match ? 1 : 0);
            if (lane == 0) s_wcnt[w] = (int)__popcll(mb);
            __syncthreads();
            int off = s_cnt;
            for (int ww = 0; ww < w; ++ww) off += s_wcnt[ww];
            off += (int)__popcll(mb & ((1ull << lane) - 1ull));
            if (match && off < CMAX) g_list[c * CMAX + off] = idx;
            __syncthreads();
            if (t == 0) {
                int tot = 0;
                for (int ww = 0; ww < 4; ++ww) tot += s_wcnt[ww];
                s_cnt = min(s_cnt + tot, CMAX);
            }
            __syncthreads();
        }
        if (t == 0) g_cnt[c] = s_cnt;
    }
}

// ---------------------------------------------------------------------------
// Kernel 2: MEGA dispatch. Classify blocks FIRST (0..255, one per CU at t=0),
// gram blocks after (256..984) co-resident to hide classify's LDS latency.
// LDS tiles k-major: gram A stride 130 (128 rows + 2; ==2 mod 32 -> staging
// writes 2-way = free), gram B / classify A stride 66, classify B stride 98.
// Inner k-loops hand-pipelined (load k+1 frags while FMA-ing k).
// ---------------------------------------------------------------------------
__global__ __launch_bounds__(256)
void mega_kernel(const float* __restrict__ instances,
                 const int*   __restrict__ labels,
                 const float* __restrict__ memory,
                 const float* __restrict__ mean_in,   // [81][2048]
                 const float* __restrict__ base_in,   // [81]
                 const int*   __restrict__ g_list,
                 const int*   __restrict__ g_cnt,
                 float* __restrict__ E,               // [81][EXT][EXT]
                 float* __restrict__ cls_out,         // [16384]
                 float* __restrict__ acc_out)         // [1]
{
    __shared__ __align__(16) char smem[26624];
    const int t = threadIdx.x;

    if (blockIdx.x >= N_CLSBLK) {
        // ================= gram role =================
        float* sA = (float*)smem;                         // [32][130] 16640 B (128 rows, k-major)
        float* sB = (float*)(smem + 16640);               // [32][66]   8448 B (64 rows, k-major)
        const float** pA = (const float**)(smem + 25088); // [128] row ptrs (1024 B)
        const float** pB = (const float**)(smem + 26112); // [64]  row ptrs (512 B)

        const int gb = blockIdx.x - N_CLSBLK;
        const int c  = gb / GR_TILES;
        const int tt = gb % GR_TILES;
        int ta, tb;
        if (tt < 5)      { ta = 0; tb = tt; }
        else if (tt < 8) { ta = 1; tb = tt - 3; }
        else             { ta = 2; tb = 4; }
        const int cnt = g_cnt[c];
        const int n = BANK + cnt;
        if (ta * 128 >= n || tb * 64 >= n) return;
        const int* li = g_list + c * CMAX;

        if (t < 128) {
            int e = ta * 128 + t; if (e >= n) e = n - 1;
            pA[t] = (e < BANK) ? memory + (size_t)(c * BANK + e) * INS_DIM
                               : instances + (size_t)li[e - BANK] * INS_DIM;
        } else if (t < 192) {
            int e = tb * 64 + (t - 128); if (e >= n) e = n - 1;
            pB[t - 128] = (e < BANK) ? memory + (size_t)(c * BANK + e) * INS_DIM
                                     : instances + (size_t)li[e - BANK] * INS_DIM;
        }
        __syncthreads();

        const int tx = t & 15;     // col group: cols tx*4 .. +3
        const int ty = t >> 4;     // row group: rows ty*8 .. +7
        double dacc[8][4];
        #pragma unroll
        for (int i = 0; i < 8; ++i)
            #pragma unroll
            for (int j = 0; j < 4; ++j) dacc[i][j] = 0.0;

        const float* arp = &sA[ty * 8];
        const float* brp = &sB[tx * 4];

        for (int k0 = 0; k0 < INS_DIM; k0 += 32) {
            #pragma unroll
            for (int jj = 0; jj < 4; ++jj) {           // A: 128 rows x 32 k
                const int u = t + 256 * jj;
                const int r = u >> 3, m4 = (u & 7) * 4;
                const float4 v = *(const float4*)(pA[r] + k0 + m4);
                sA[(m4 + 0) * 130 + r] = v.x;
                sA[(m4 + 1) * 130 + r] = v.y;
                sA[(m4 + 2) * 130 + r] = v.z;
                sA[(m4 + 3) * 130 + r] = v.w;
            }
            #pragma unroll
            for (int jj = 0; jj < 2; ++jj) {           // B: 64 rows x 32 k
                const int u = t + 256 * jj;
                const int r = u >> 3, m4 = (u & 7) * 4;
                const float4 v = *(const float4*)(pB[r] + k0 + m4);
                sB[(m4 + 0) * 66 + r] = v.x;
                sB[(m4 + 1) * 66 + r] = v.y;
                sB[(m4 + 2) * 66 + r] = v.z;
                sB[(m4 + 3) * 66 + r] = v.w;
            }
            __syncthreads();

            float cacc[8][4];
            #pragma unroll
            for (int i = 0; i < 8; ++i)
                #pragma unroll
                for (int j = 0; j < 4; ++j) cacc[i][j] = 0.0f;

            float2 fa0, fa1, fa2, fa3, fa4, fa5;   // cur frags
            float2 fb0, fb1, fb2, fb3, fb4, fb5;   // next frags
            #define GLD(d0,d1,d2,d3,d4,d5,kk) { \
                const float* ap_ = arp + (kk) * 130; \
                d0 = *(const float2*)(ap_);     d1 = *(const float2*)(ap_ + 2); \
                d2 = *(const float2*)(ap_ + 4); d3 = *(const float2*)(ap_ + 6); \
                const float* bp_ = brp + (kk) * 66; \
                d4 = *(const float2*)(bp_);     d5 = *(const float2*)(bp_ + 2); }
            #define GFMA(s0,s1,s2,s3,s4,s5) { \
                const float av_[8] = { s0.x, s0.y, s1.x, s1.y, s2.x, s2.y, s3.x, s3.y }; \
                const float bv_[4] = { s4.x, s4.y, s5.x, s5.y }; \
                _Pragma("unroll") \
                for (int i_ = 0; i_ < 8; ++i_) \
                    _Pragma("unroll") \
                    for (int j_ = 0; j_ < 4; ++j_) cacc[i_][j_] += av_[i_] * bv_[j_]; }

            GLD(fa0, fa1, fa2, fa3, fa4, fa5, 0);
            #pragma unroll
            for (int k = 0; k < 32; k += 2) {
                GLD(fb0, fb1, fb2, fb3, fb4, fb5, k + 1);
                GFMA(fa0, fa1, fa2, fa3, fa4, fa5);
                if (k + 2 < 32) { GLD(fa0, fa1, fa2, fa3, fa4, fa5, k + 2); }
                GFMA(fb0, fb1, fb2, fb3, fb4, fb5);
            }
            #undef GLD
            #undef GFMA

            #pragma unroll
            for (int i = 0; i < 8; ++i)
                #pragma unroll
                for (int j = 0; j < 4; ++j) dacc[i][j] += (double)cacc[i][j];
            __syncthreads();
        }

        float* Ec = E + (size_t)c * EXT * EXT;
        #pragma unroll
        for (int i = 0; i < 8; ++i) {
            const int a = ta * 128 + ty * 8 + i;
            if (a < EXT) {
                float* row = Ec + (size_t)a * EXT + tb * 64 + tx * 4;
                #pragma unroll
                for (int j = 0; j < 4; ++j) {
                    const int b = tb * 64 + tx * 4 + j;
                    if (b < EXT) row[j] = (float)dacc[i][j];
                }
            }
        }
        return;
    }

    // ================= classify role =================
    {
        float*  sAt  = (float*)smem;                  // [32][66] 8448 B (64 inst, k-major)
        float*  sBt  = (float*)(smem + 8448);         // [32][98] 12544 B (81 cls, k-major)
        double* redS = (double*)(smem + 20992);       // [64][4]
        int*    redC = (int*)(smem + 23040);          // [64][4]

        const int ig = t & 15;
        const int cg = t >> 4;
        const int i0 = blockIdx.x * 64;
        const int w = t >> 6, lane = t & 63;

        // zero pad cols 81..97 once (never overwritten by staging)
        for (int u = t; u < 32 * 17; u += 256) {
            const int kk = u / 17, cc2 = 81 + (u % 17);
            sBt[kk * 98 + cc2] = 0.0f;
        }

        double dacc[4][6];
        #pragma unroll
        for (int q = 0; q < 4; ++q)
            #pragma unroll
            for (int j = 0; j < 6; ++j) dacc[q][j] = 0.0;

        const float* arp = &sAt[ig * 4];
        const float* brp = &sBt[cg * 6];

        for (int k0 = 0; k0 < INS_DIM; k0 += 32) {
            #pragma unroll
            for (int jj = 0; jj < 2; ++jj) {           // A: 64 rows x 32 k
                const int u = t + 256 * jj;
                const int r = u >> 3, m4 = (u & 7) * 4;
                const float4 v = *(const float4*)(instances + (size_t)(i0 + r) * INS_DIM + k0 + m4);
                sAt[(m4 + 0) * 66 + r] = v.x;
                sAt[(m4 + 1) * 66 + r] = v.y;
                sAt[(m4 + 2) * 66 + r] = v.z;
                sAt[(m4 + 3) * 66 + r] = v.w;
            }
            for (int u = t; u < 81 * 8; u += 256) {    // B^T: 81 classes x 32 k
                const int cc = u >> 3, m4 = (u & 7) * 4;
                const float4 v = *(const float4*)(mean_in + (size_t)cc * INS_DIM + k0 + m4);
                sBt[(m4 + 0) * 98 + cc] = v.x;
                sBt[(m4 + 1) * 98 + cc] = v.y;
                sBt[(m4 + 2) * 98 + cc] = v.z;
                sBt[(m4 + 3) * 98 + cc] = v.w;
            }
            __syncthreads();

            float cacc[4][6];
            #pragma unroll
            for (int q = 0; q < 4; ++q)
                #pragma unroll
                for (int j = 0; j < 6; ++j) cacc[q][j] = 0.0f;

            float2 fa0, fa1, fa2, fa3, fa4;   // cur: a01,a23,b01,b23,b45
            float2 fb0, fb1, fb2, fb3, fb4;   // next
            #define CLD(d0,d1,d2,d3,d4,kk) { \
                const float* ap_ = arp + (kk) * 66; \
                d0 = *(const float2*)(ap_); d1 = *(const float2*)(ap_ + 2); \
                const float* bp_ = brp + (kk) * 98; \
                d2 = *(const float2*)(bp_); d3 = *(const float2*)(bp_ + 2); \
                d4 = *(const float2*)(bp_ + 4); }
            #define CFMA(s0,s1,s2,s3,s4) { \
                const float av_[4] = { s0.x, s0.y, s1.x, s1.y }; \
                const float bv_[6] = { s2.x, s2.y, s3.x, s3.y, s4.x, s4.y }; \
                _Pragma("unroll") \
                for (int q_ = 0; q_ < 4; ++q_) \
                    _Pragma("unroll") \
                    for (int j_ = 0; j_ < 6; ++j_) cacc[q_][j_] += av_[q_] * bv_[j_]; }

            CLD(fa0, fa1, fa2, fa3, fa4, 0);
            #pragma unroll
            for (int k = 0; k < 32; k += 2) {
                CLD(fb0, fb1, fb2, fb3, fb4, k + 1);
                CFMA(fa0, fa1, fa2, fa3, fa4);
                if (k + 2 < 32) { CLD(fa0, fa1, fa2, fa3, fa4, k + 2); }
                CFMA(fb0, fb1, fb2, fb3, fb4);
            }
            #undef CLD
            #undef CFMA

            #pragma unroll
            for (int q = 0; q < 4; ++q)
                #pragma unroll
                for (int j = 0; j < 6; ++j) dacc[q][j] += (double)cacc[q][j];
            __syncthreads();
        }

        // per-thread argmin over 6 classes (ascending, strict < = first-min)
        float bvals[6];
        #pragma unroll
        for (int j = 0; j < 6; ++j) {
            const int cc = cg * 6 + j;
            bvals[j] = (cc < N_CLS) ? base_in[cc] : 0.0f;
        }
        double tbv[4]; int tbc[4];
        #pragma unroll
        for (int q = 0; q < 4; ++q) {
            double best = 1e300; int bestc = 0x7fffffff;
            #pragma unroll
            for (int j = 0; j < 6; ++j) {
                const int cc = cg * 6 + j;
                if (cc < N_CLS) {
                    const double sc = (double)bvals[j] - 2.0 * dacc[q][j];
                    if (sc < best) { best = sc; bestc = cc; }
                }
            }
            tbv[q] = best; tbc[q] = bestc;
        }
        #pragma unroll
        for (int q = 0; q < 4; ++q) {
            #pragma unroll
            for (int off = 16; off <= 32; off <<= 1) {
                const double ov = __shfl_xor(tbv[q], off, 64);
                const int    oc = __shfl_xor(tbc[q], off, 64);
                if (ov < tbv[q] || (ov == tbv[q] && oc < tbc[q])) { tbv[q] = ov; tbc[q] = oc; }
            }
        }
        if (lane < 16) {
            #pragma unroll
            for (int q = 0; q < 4; ++q) {
                redS[(lane * 4 + q) * 4 + w] = tbv[q];
                redC[(lane * 4 + q) * 4 + w] = tbc[q];
            }
        }
        __syncthreads();
        if (t < 64) {
            double best = redS[t * 4 + 0]; int bc = redC[t * 4 + 0];
            #pragma unroll
            for (int g = 1; g < 4; ++g) {
                const double v = redS[t * 4 + g];
                if (v < best) { best = v; bc = redC[t * 4 + g]; }
            }
            const int gi = i0 + t;
            cls_out[gi] = (float)bc;
            const bool ok = (bc == labels[gi]);
            const unsigned long long m = __ballot(ok ? 1 : 0);
            if (t == 0) atomicAdd(acc_out, (float)__popcll(m) * (1.0f / 16384.0f));
        }
    }
}

// ---------------------------------------------------------------------------
// Kernel 3: sequential scan — pure E-table lookups. 1 wave per class.
// ---------------------------------------------------------------------------
__global__ __launch_bounds__(64)
void scan_kernel(const int* __restrict__ memory_pos,
                 const int* __restrict__ g_cnt,
                 const float* __restrict__ E,
                 int* __restrict__ ids_out,    // [81][10] ext ids
                 float* __restrict__ pos_out)  // [81]
{
    const int c = blockIdx.x;
    const int lane = threadIdx.x;
    const int cnt = g_cnt[c];
    const int p0 = memory_pos[c];
    const float* Ec = E + (size_t)c * EXT * EXT;

    int eid = lane;
    double nrm = (lane < BANK) ? (double)Ec[(size_t)lane * EXT + lane] : 0.0;

    int k0 = BANK - p0; if (k0 > cnt) k0 = cnt; if (k0 < 0) k0 = 0;
    if (lane >= p0 && lane < BANK) {
        const int j = lane - p0;
        if (j < k0) { eid = BANK + j; nrm = (double)Ec[(size_t)(BANK + j) * EXT + (BANK + j)]; }
    }
    const int p = p0 + k0;

    if (k0 < cnt) {
        float dotc = 0.0f;
        double xnc = (double)Ec[(size_t)(BANK + k0) * EXT + (BANK + k0)];
        if (lane < BANK) dotc = Ec[(size_t)eid * EXT + (BANK + k0)];
        for (int i = k0; i < cnt; ++i) {
            const double xn = xnc;
            double bv = (lane < BANK) ? (nrm + xn - 2.0 * (double)dotc) : -1.0e300;
            int bi = lane;
            #pragma unroll
            for (int off = 8; off >= 1; off >>= 1) {
                const double ov = __shfl_down(bv, off, 16);
                const int    oi = __shfl_down(bi, off, 16);
                if (ov > bv || (ov == bv && oi < bi)) { bv = ov; bi = oi; }
            }
            const int widx = __shfl(bi, 0, 64);
            if (lane == widx) { eid = BANK + i; nrm = xn; }
            if (i + 1 < cnt) {
                xnc = (double)Ec[(size_t)(BANK + i + 1) * EXT + (BANK + i + 1)];
                if (lane < BANK) dotc = Ec[(size_t)eid * EXT + (BANK + i + 1)];
            }
        }
    }
    if (lane < BANK) ids_out[c * BANK + lane] = eid;
    if (lane == 0) pos_out[c] = (float)p;
}

// ---------------------------------------------------------------------------
// Kernel 4: emit final bank rows
// ---------------------------------------------------------------------------
__global__ __launch_bounds__(256)
void emit_kernel(const float* __restrict__ instances,
                 const float* __restrict__ memory,
                 const int* __restrict__ g_list,
                 const int* __restrict__ ids,
                 float* __restrict__ mem_out)
{
    const int c = blockIdx.x / BANK;
    const int s = blockIdx.x % BANK;
    const int t = threadIdx.x;
    const int eid = ids[c * BANK + s];
    const float* src = (eid < BANK)
        ? memory + ((size_t)(c * BANK + eid)) * INS_DIM
        : instances + (size_t)g_list[c * CMAX + (eid - BANK)] * INS_DIM;
    float* dst = mem_out + ((size_t)(c * BANK + s)) * INS_DIM;
    #pragma unroll
    for (int j = 0; j < 2; ++j) {
        const int d4 = (t + j * 256) * 4;
        *(float4*)(dst + d4) = *(const float4*)(src + d4);
    }
}

// ---------------------------------------------------------------------------
extern "C" void kernel_launch(void* const* d_in, const int* in_sizes, int n_in,
                              void* d_out, int out_size, void* d_ws, size_t ws_size,
                              hipStream_t stream)
{
    const float* instances = (const float*)d_in[0];
    const int*   labels    = (const int*)  d_in[1];
    const float* memory    = (const float*)d_in[2];
    const int*   mpos      = (const int*)  d_in[3];

    float* out      = (float*)d_out;
    float* cls_out  = out;                                   // [16384]
    float* acc_out  = out + N_INS;                           // [1]
    float* mem_out  = out + N_INS + 1;                       // [81*10*2048]
    float* pos_out  = mem_out + (size_t)N_CLS * BANK * INS_DIM; // [81]

    // scratch inside new_mem output region; emit_kernel overwrites it last
    float* mean_scr = mem_out;                               // [81*2048]
    float* base_scr = mem_out + (size_t)N_CLS * INS_DIM;     // [81]

    // workspace (~30.1 MB)
    float* ws_E    = (float*)d_ws;                           // [81*EXT*EXT]
    int*   ws_list = (int*)(ws_E + (size_t)N_CLS * EXT * EXT);
    int*   ws_cnt  = ws_list + N_CLS * CMAX;
    int*   ws_ids  = ws_cnt + N_CLS;

    hipMemsetAsync(acc_out, 0, sizeof(float), stream);
    hipLaunchKernelGGL(prep_list_kernel, dim3(2 * N_CLS), dim3(256), 0, stream,
                       memory, labels, mean_scr, base_scr, ws_list, ws_cnt);
    hipLaunchKernelGGL(mega_kernel, dim3(GRID_ALL), dim3(256), 0, stream,
                       instances, labels, memory, mean_scr, base_scr,
                       ws_list, ws_cnt, ws_E, cls_out, acc_out);
    hipLaunchKernelGGL(scan_kernel, dim3(N_CLS), dim3(64), 0, stream,
                       mpos, ws_cnt, ws_E, ws_ids, pos_out);
    hipLaunchKernelGGL(emit_kernel, dim3(N_CLS * BANK), dim3(256), 0, stream,
                       instances, memory, ws_list, ws_ids, mem_out);
}

// Round 6
// 930.204 us; speedup vs baseline: 1.2954x; 1.2954x over previous
//
#include <hip/hip_runtime.h>
#include <cstdint>
#include <cstddef>

#define N_INS    16384
#define INS_DIM  2048
#define N_CLS    81
#define BANK     10
#define CMAX     288    // max instances/class (mean 202, sd 14; fixed seed max ~252)
#define EXT      304    // extended Gram dim/stride: 10 + CMAX + pad
#define GR_TILES 9      // 128x64 tiles covering upper triangle of EXT x EXT
#define N_CLSBLK (N_INS / 64)          // 256 classify blocks, FIRST in grid
#define GRID_ALL (N_CLSBLK + N_CLS * GR_TILES)

// ---------------------------------------------------------------------------
// Kernel 1: fused prep (mean + ||mean||^2) and per-class ordered list build
// ---------------------------------------------------------------------------
__global__ __launch_bounds__(256)
void prep_list_kernel(const float* __restrict__ memory,
                      const int*   __restrict__ labels,
                      float* __restrict__ mean_out,   // [81][2048]
                      float* __restrict__ base_out,   // [81]
                      int* __restrict__ g_list,       // [81][CMAX]
                      int* __restrict__ g_cnt)        // [81]
{
    __shared__ double sred[4];
    __shared__ int s_wcnt[4];
    __shared__ int s_cnt;
    const int t = threadIdx.x;
    const int w = t >> 6, lane = t & 63;

    if (blockIdx.x < N_CLS) {
        const int c = blockIdx.x;
        double nrm = 0.0;
        #pragma unroll
        for (int rep = 0; rep < 2; ++rep) {
            const int d4 = (t + rep * 256) * 4;
            float sx = 0.f, sy = 0.f, sz = 0.f, sw = 0.f;
            #pragma unroll
            for (int b = 0; b < BANK; ++b) {
                const float4 v = *(const float4*)(memory + ((size_t)(c * BANK + b)) * INS_DIM + d4);
                sx += v.x; sy += v.y; sz += v.z; sw += v.w;
            }
            sx /= 10.0f; sy /= 10.0f; sz /= 10.0f; sw /= 10.0f;
            *(float4*)(mean_out + (size_t)c * INS_DIM + d4) = make_float4(sx, sy, sz, sw);
            nrm += (double)sx * sx + (double)sy * sy + (double)sz * sz + (double)sw * sw;
        }
        #pragma unroll
        for (int off = 32; off >= 1; off >>= 1) nrm += __shfl_xor(nrm, off, 64);
        if (lane == 0) sred[w] = nrm;
        __syncthreads();
        if (t == 0) base_out[c] = (float)(sred[0] + sred[1] + sred[2] + sred[3]);
    } else {
        const int c = blockIdx.x - N_CLS;
        if (t == 0) s_cnt = 0;
        __syncthreads();
        for (int base = 0; base < N_INS; base += 256) {
            const int idx = base + t;
            const bool match = (labels[idx] == c);
            const unsigned long long mb = __ballot(match ? 1 : 0);
            if (lane == 0) s_wcnt[w] = (int)__popcll(mb);
            __syncthreads();
            int off = s_cnt;
            for (int ww = 0; ww < w; ++ww) off += s_wcnt[ww];
            off += (int)__popcll(mb & ((1ull << lane) - 1ull));
            if (match && off < CMAX) g_list[c * CMAX + off] = idx;
            __syncthreads();
            if (t == 0) {
                int tot = 0;
                for (int ww = 0; ww < 4; ++ww) tot += s_wcnt[ww];
                s_cnt = min(s_cnt + tot, CMAX);
            }
            __syncthreads();
        }
        if (t == 0) g_cnt[c] = s_cnt;
    }
}

// ---------------------------------------------------------------------------
// Kernel 2: MEGA dispatch — round-3 proven code bodies, ROLE ORDER FLIPPED:
// classify = blocks 0..255 (one per CU at t=0), gram = blocks 256..984
// co-resident behind it (VGPR 80 -> 6 waves/SIMD; LDS 27KB -> 5 blocks/CU),
// so gram's VALU work hides classify's exposed LDS latency.
// ---------------------------------------------------------------------------
__global__ __launch_bounds__(256)
void mega_kernel(const float* __restrict__ instances,
                 const int*   __restrict__ labels,
                 const float* __restrict__ memory,
                 const float* __restrict__ mean_in,   // [81][2048]
                 const float* __restrict__ base_in,   // [81]
                 const int*   __restrict__ g_list,
                 const int*   __restrict__ g_cnt,
                 float* __restrict__ E,               // [81][EXT][EXT]
                 float* __restrict__ cls_out,         // [16384]
                 float* __restrict__ acc_out)         // [1]
{
    __shared__ __align__(16) char smem[27200];
    const int t = threadIdx.x;

    if (blockIdx.x >= N_CLSBLK) {
        // ================= gram role (round-3 body) =================
        float* sA = (float*)smem;                         // [32][132] 16896 B
        float* sB = (float*)(smem + 16896);               // [32][68]   8704 B
        const float** pA = (const float**)(smem + 25600); // [128] row ptrs
        const float** pB = (const float**)(smem + 26624); // [64]  row ptrs

        const int gb = blockIdx.x - N_CLSBLK;
        const int c  = gb / GR_TILES;
        const int tt = gb % GR_TILES;
        int ta, tb;
        if (tt < 5)      { ta = 0; tb = tt; }
        else if (tt < 8) { ta = 1; tb = tt - 3; }
        else             { ta = 2; tb = 4; }
        const int cnt = g_cnt[c];
        const int n = BANK + cnt;
        if (ta * 128 >= n || tb * 64 >= n) return;
        const int* li = g_list + c * CMAX;

        if (t < 128) {
            int e = ta * 128 + t; if (e >= n) e = n - 1;
            pA[t] = (e < BANK) ? memory + (size_t)(c * BANK + e) * INS_DIM
                               : instances + (size_t)li[e - BANK] * INS_DIM;
        } else if (t < 192) {
            int e = tb * 64 + (t - 128); if (e >= n) e = n - 1;
            pB[t - 128] = (e < BANK) ? memory + (size_t)(c * BANK + e) * INS_DIM
                                     : instances + (size_t)li[e - BANK] * INS_DIM;
        }
        __syncthreads();

        const int tx = t & 15;     // col group: cols tx*4 .. +3
        const int ty = t >> 4;     // row group: rows ty*8 .. +7
        double dacc[8][4];
        #pragma unroll
        for (int i = 0; i < 8; ++i)
            #pragma unroll
            for (int j = 0; j < 4; ++j) dacc[i][j] = 0.0;

        for (int k0 = 0; k0 < INS_DIM; k0 += 32) {
            #pragma unroll
            for (int jj = 0; jj < 4; ++jj) {           // A: 128 rows x 32 k
                const int u = t + 256 * jj;
                const int r = u >> 3, m4 = (u & 7) * 4;
                const float4 v = *(const float4*)(pA[r] + k0 + m4);
                sA[(m4 + 0) * 132 + r] = v.x;
                sA[(m4 + 1) * 132 + r] = v.y;
                sA[(m4 + 2) * 132 + r] = v.z;
                sA[(m4 + 3) * 132 + r] = v.w;
            }
            #pragma unroll
            for (int jj = 0; jj < 2; ++jj) {           // B: 64 rows x 32 k
                const int u = t + 256 * jj;
                const int r = u >> 3, m4 = (u & 7) * 4;
                const float4 v = *(const float4*)(pB[r] + k0 + m4);
                sB[(m4 + 0) * 68 + r] = v.x;
                sB[(m4 + 1) * 68 + r] = v.y;
                sB[(m4 + 2) * 68 + r] = v.z;
                sB[(m4 + 3) * 68 + r] = v.w;
            }
            __syncthreads();

            float cacc[8][4];
            #pragma unroll
            for (int i = 0; i < 8; ++i)
                #pragma unroll
                for (int j = 0; j < 4; ++j) cacc[i][j] = 0.0f;

            #pragma unroll 4
            for (int k = 0; k < 32; ++k) {
                const float4 a0 = *(const float4*)&sA[k * 132 + ty * 8];
                const float4 a1 = *(const float4*)&sA[k * 132 + ty * 8 + 4];
                const float4 b  = *(const float4*)&sB[k * 68 + tx * 4];
                const float av[8] = { a0.x, a0.y, a0.z, a0.w, a1.x, a1.y, a1.z, a1.w };
                const float bv[4] = { b.x, b.y, b.z, b.w };
                #pragma unroll
                for (int i = 0; i < 8; ++i)
                    #pragma unroll
                    for (int j = 0; j < 4; ++j) cacc[i][j] += av[i] * bv[j];
            }
            #pragma unroll
            for (int i = 0; i < 8; ++i)
                #pragma unroll
                for (int j = 0; j < 4; ++j) dacc[i][j] += (double)cacc[i][j];
            __syncthreads();
        }

        float* Ec = E + (size_t)c * EXT * EXT;
        #pragma unroll
        for (int i = 0; i < 8; ++i) {
            const int a = ta * 128 + ty * 8 + i;
            if (a < EXT) {
                float* row = Ec + (size_t)a * EXT + tb * 64 + tx * 4;
                #pragma unroll
                for (int j = 0; j < 4; ++j) {
                    const int b = tb * 64 + tx * 4 + j;
                    if (b < EXT) row[j] = (float)dacc[i][j];
                }
            }
        }
        return;
    }

    // ================= classify role (round-3 body, blocks 0..255) =========
    {
        float*  sAt  = (float*)smem;                  // [64][33]  8448 B (row-major)
        float*  sBt  = (float*)(smem + 8448);         // [32][100] 12800 B (k-major)
        double* redS = (double*)(smem + 21248);       // [64][4]
        int*    redC = (int*)(smem + 23296);          // [64][4]

        const int ig = t & 15;
        const int cg = t >> 4;
        const int i0 = blockIdx.x * 64;
        const int w = t >> 6, lane = t & 63;

        // zero pad cols 81..99 once (never overwritten by staging)
        for (int u = t; u < 32 * 19; u += 256) {
            const int kk = u / 19, cc2 = 81 + (u % 19);
            sBt[kk * 100 + cc2] = 0.0f;
        }

        double dacc[4][6];
        #pragma unroll
        for (int q = 0; q < 4; ++q)
            #pragma unroll
            for (int j = 0; j < 6; ++j) dacc[q][j] = 0.0;

        for (int k0 = 0; k0 < INS_DIM; k0 += 32) {
            #pragma unroll
            for (int jj = 0; jj < 2; ++jj) {           // A: 64 rows x 32 k
                const int u = t + 256 * jj;
                const int r = u >> 3, m4 = (u & 7) * 4;
                const float4 v = *(const float4*)(instances + (size_t)(i0 + r) * INS_DIM + k0 + m4);
                float* dst = &sAt[r * 33 + m4];
                dst[0] = v.x; dst[1] = v.y; dst[2] = v.z; dst[3] = v.w;
            }
            for (int u = t; u < 81 * 8; u += 256) {    // B^T: 81 classes x 32 k
                const int cc = u >> 3, m4 = (u & 7) * 4;
                const float4 v = *(const float4*)(mean_in + (size_t)cc * INS_DIM + k0 + m4);
                sBt[(m4 + 0) * 100 + cc] = v.x;
                sBt[(m4 + 1) * 100 + cc] = v.y;
                sBt[(m4 + 2) * 100 + cc] = v.z;
                sBt[(m4 + 3) * 100 + cc] = v.w;
            }
            __syncthreads();

            float cacc[4][6];
            #pragma unroll
            for (int q = 0; q < 4; ++q)
                #pragma unroll
                for (int j = 0; j < 6; ++j) cacc[q][j] = 0.0f;

            for (int k = 0; k < 32; ++k) {
                float a[4];
                #pragma unroll
                for (int q = 0; q < 4; ++q) a[q] = sAt[(ig * 4 + q) * 33 + k];
                const float* bp = &sBt[k * 100 + cg * 6];
                const float2 b01 = *(const float2*)(bp);
                const float2 b23 = *(const float2*)(bp + 2);
                const float2 b45 = *(const float2*)(bp + 4);
                const float bv[6] = { b01.x, b01.y, b23.x, b23.y, b45.x, b45.y };
                #pragma unroll
                for (int q = 0; q < 4; ++q)
                    #pragma unroll
                    for (int j = 0; j < 6; ++j) cacc[q][j] += a[q] * bv[j];
            }
            #pragma unroll
            for (int q = 0; q < 4; ++q)
                #pragma unroll
                for (int j = 0; j < 6; ++j) dacc[q][j] += (double)cacc[q][j];
            __syncthreads();
        }

        // per-thread argmin over 6 classes (ascending, strict < = first-min)
        float bvals[6];
        #pragma unroll
        for (int j = 0; j < 6; ++j) {
            const int cc = cg * 6 + j;
            bvals[j] = (cc < N_CLS) ? base_in[cc] : 0.0f;
        }
        double tbv[4]; int tbc[4];
        #pragma unroll
        for (int q = 0; q < 4; ++q) {
            double best = 1e300; int bestc = 0x7fffffff;
            #pragma unroll
            for (int j = 0; j < 6; ++j) {
                const int cc = cg * 6 + j;
                if (cc < N_CLS) {
                    const double sc = (double)bvals[j] - 2.0 * dacc[q][j];
                    if (sc < best) { best = sc; bestc = cc; }
                }
            }
            tbv[q] = best; tbc[q] = bestc;
        }
        #pragma unroll
        for (int q = 0; q < 4; ++q) {
            #pragma unroll
            for (int off = 16; off <= 32; off <<= 1) {
                const double ov = __shfl_xor(tbv[q], off, 64);
                const int    oc = __shfl_xor(tbc[q], off, 64);
                if (ov < tbv[q] || (ov == tbv[q] && oc < tbc[q])) { tbv[q] = ov; tbc[q] = oc; }
            }
        }
        if (lane < 16) {
            #pragma unroll
            for (int q = 0; q < 4; ++q) {
                redS[(lane * 4 + q) * 4 + w] = tbv[q];
                redC[(lane * 4 + q) * 4 + w] = tbc[q];
            }
        }
        __syncthreads();
        if (t < 64) {
            double best = redS[t * 4 + 0]; int bc = redC[t * 4 + 0];
            #pragma unroll
            for (int g = 1; g < 4; ++g) {
                const double v = redS[t * 4 + g];
                if (v < best) { best = v; bc = redC[t * 4 + g]; }
            }
            const int gi = i0 + t;
            cls_out[gi] = (float)bc;
            const bool ok = (bc == labels[gi]);
            const unsigned long long m = __ballot(ok ? 1 : 0);
            if (t == 0) atomicAdd(acc_out, (float)__popcll(m) * (1.0f / 16384.0f));
        }
    }
}

// ---------------------------------------------------------------------------
// Kernel 3: fused scan + emit. Wave 0 runs the sequential scan with BOTH
// next-step dot candidates prefetched BEFORE the argmax (the winner's new
// content is always instance i, so dot_new = E[B+i][B+i+1] is known early);
// the dependent gather leaves the critical path. Then all 256 threads copy.
// ---------------------------------------------------------------------------
__global__ __launch_bounds__(256)
void scan_emit_kernel(const int* __restrict__ memory_pos,
                      const int* __restrict__ g_cnt,
                      const int* __restrict__ g_list,
                      const float* __restrict__ E,
                      const float* __restrict__ instances,
                      const float* __restrict__ memory,
                      float* __restrict__ mem_out,   // [81][10][2048]
                      float* __restrict__ pos_out)   // [81]
{
    __shared__ int s_ids[BANK];
    const int c = blockIdx.x;
    const int t = threadIdx.x;
    const int cnt = g_cnt[c];
    const int p0 = memory_pos[c];
    const float* Ec = E + (size_t)c * EXT * EXT;

    if (t < 64) {
        const int lane = t;
        int eid = lane;
        double nrm = (lane < BANK) ? (double)Ec[(size_t)lane * EXT + lane] : 0.0;

        int k0 = BANK - p0; if (k0 > cnt) k0 = cnt; if (k0 < 0) k0 = 0;
        if (lane >= p0 && lane < BANK) {
            const int j = lane - p0;
            if (j < k0) { eid = BANK + j; nrm = (double)Ec[(size_t)(BANK + j) * EXT + (BANK + j)]; }
        }
        const int p = p0 + k0;

        if (k0 < cnt) {
            float dotc = 0.0f;
            double xnc = (double)Ec[(size_t)(BANK + k0) * EXT + (BANK + k0)];
            if (lane < BANK) dotc = Ec[(size_t)eid * EXT + (BANK + k0)];
            for (int i = k0; i < cnt; ++i) {
                // ---- prefetch for i+1 (independent of this step's argmax) ----
                const int ip = (i + 1 < cnt) ? (i + 1) : i;
                const double xn1 = (double)Ec[(size_t)(BANK + ip) * EXT + (BANK + ip)];
                float dk = 0.0f;
                if (lane < BANK) dk = Ec[(size_t)eid * EXT + (BANK + ip)];
                const float dn = Ec[(size_t)(BANK + i) * EXT + (BANK + ip)];

                // ---- argmax over slots (strict > : first-max) ----
                double bv = (lane < BANK) ? (nrm + xnc - 2.0 * (double)dotc) : -1.0e300;
                int bi = lane;
                #pragma unroll
                for (int off = 8; off >= 1; off >>= 1) {
                    const double ov = __shfl_down(bv, off, 16);
                    const int    oi = __shfl_down(bi, off, 16);
                    if (ov > bv || (ov == bv && oi < bi)) { bv = ov; bi = oi; }
                }
                const int widx = __shfl(bi, 0, 64);

                // ---- state update via select (no dependent load) ----
                if (lane == widx) { eid = BANK + i; nrm = xnc; dotc = dn; }
                else              { dotc = dk; }
                xnc = xn1;
            }
        }
        if (lane < BANK) s_ids[lane] = eid;
        if (lane == 0) pos_out[c] = (float)p;
    }
    __syncthreads();

    const int* li = g_list + c * CMAX;
    for (int s = 0; s < BANK; ++s) {
        const int eid = s_ids[s];
        const float* src = (eid < BANK)
            ? memory + ((size_t)(c * BANK + eid)) * INS_DIM
            : instances + (size_t)li[eid - BANK] * INS_DIM;
        float* dst = mem_out + ((size_t)(c * BANK + s)) * INS_DIM;
        #pragma unroll
        for (int j = 0; j < 2; ++j) {
            const int d4 = (t + j * 256) * 4;
            *(float4*)(dst + d4) = *(const float4*)(src + d4);
        }
    }
}

// ---------------------------------------------------------------------------
extern "C" void kernel_launch(void* const* d_in, const int* in_sizes, int n_in,
                              void* d_out, int out_size, void* d_ws, size_t ws_size,
                              hipStream_t stream)
{
    const float* instances = (const float*)d_in[0];
    const int*   labels    = (const int*)  d_in[1];
    const float* memory    = (const float*)d_in[2];
    const int*   mpos      = (const int*)  d_in[3];

    float* out      = (float*)d_out;
    float* cls_out  = out;                                   // [16384]
    float* acc_out  = out + N_INS;                           // [1]
    float* mem_out  = out + N_INS + 1;                       // [81*10*2048]
    float* pos_out  = mem_out + (size_t)N_CLS * BANK * INS_DIM; // [81]

    // scratch inside new_mem output region; scan_emit overwrites it last
    float* mean_scr = mem_out;                               // [81*2048]
    float* base_scr = mem_out + (size_t)N_CLS * INS_DIM;     // [81]

    // workspace (~30.1 MB)
    float* ws_E    = (float*)d_ws;                           // [81*EXT*EXT]
    int*   ws_list = (int*)(ws_E + (size_t)N_CLS * EXT * EXT);
    int*   ws_cnt  = ws_list + N_CLS * CMAX;

    hipMemsetAsync(acc_out, 0, sizeof(float), stream);
    hipLaunchKernelGGL(prep_list_kernel, dim3(2 * N_CLS), dim3(256), 0, stream,
                       memory, labels, mean_scr, base_scr, ws_list, ws_cnt);
    hipLaunchKernelGGL(mega_kernel, dim3(GRID_ALL), dim3(256), 0, stream,
                       instances, labels, memory, mean_scr, base_scr,
                       ws_list, ws_cnt, ws_E, cls_out, acc_out);
    hipLaunchKernelGGL(scan_emit_kernel, dim3(N_CLS), dim3(256), 0, stream,
                       mpos, ws_cnt, ws_list, ws_E, instances, memory,
                       mem_out, pos_out);
}